// Round 8
// baseline (693.268 us; speedup 1.0000x reference)
//
#include <hip/hip_runtime.h>
#include <hip/hip_bf16.h>
#include <stdint.h>
#include <math.h>

typedef __bf16 bf16_t;
typedef __bf16 bf16x8 __attribute__((ext_vector_type(8)));
typedef __bf16 bf16x4 __attribute__((ext_vector_type(4)));
typedef float  f32x4  __attribute__((ext_vector_type(4)));

// Problem constants: B=16,H=64,W=80,C=256; GH=8,GW=10; heads=8,DH=32; INNER=1024
//
// FRAG layout (A and B^T operands), X[M rows][K cols], K32=K/32:
//   element (m,k): g=m>>4, lnr=m&15, kk=k>>5, q=(k&31)>>3, j=k&7
//   addr = ((g*K32 + kk)*64 + q*16 + lnr)*8 + j
// One MFMA fragment = one contiguous 1KB wave-load: base + ((g*K32+kk)*64 + lane)*8

__device__ __forceinline__ int map_p_to_g(int p) {
    int w = p / 80, n = p - w * 80;
    int b  = w >> 6, h2 = (w >> 3) & 7, w2 = w & 7;
    int gh = n / 10, gw = n - gh * 10;
    return b * 5120 + (gh * 8 + h2) * 80 + (gw * 8 + w2);
}

// ---------------- weight convert: fp32 [K][N] -> bf16 frag layout of Bt[N][K] ----------------
__global__ __launch_bounds__(256) void wconv_k(const float* __restrict__ in,
                                               bf16_t* __restrict__ out, int N, int K32)
{
    int c  = blockIdx.x * 256 + threadIdx.x;
    int gk = c >> 6, l = c & 63;
    int kk = gk % K32, g = gk / K32;
    int n  = g * 16 + (l & 15);
    int kb = kk * 32 + (l >> 4) * 8;
    bf16x8 v;
#pragma unroll
    for (int j = 0; j < 8; ++j)
        v[j] = (bf16_t)in[(size_t)(kb + j) * N + n];
    *(bf16x8*)(out + (size_t)c * 8) = v;
}

// ---------------- LayerNorm (one wave per row) -> frag-layout output (K=256) ----------------
template <int PERM>
__global__ __launch_bounds__(256) void ln_k(const float* __restrict__ in,
                                            const float* __restrict__ gg,
                                            const float* __restrict__ bb,
                                            bf16_t* __restrict__ o)
{
    int row  = blockIdx.x * 4 + (threadIdx.x >> 6);
    int lane = threadIdx.x & 63;
    const float4 xv = *(const float4*)(in + (size_t)row * 256 + lane * 4);
    float s = xv.x + xv.y + xv.z + xv.w;
#pragma unroll
    for (int m = 1; m < 64; m <<= 1) s += __shfl_xor(s, m, 64);
    float mean = s * (1.f / 256.f);
    float d0 = xv.x - mean, d1 = xv.y - mean, d2 = xv.z - mean, d3 = xv.w - mean;
    float v = d0 * d0 + d1 * d1 + d2 * d2 + d3 * d3;
#pragma unroll
    for (int m = 1; m < 64; m <<= 1) v += __shfl_xor(v, m, 64);
    float rstd = rsqrtf(v * (1.f / 256.f) + 1e-5f);
    const float4 gv = *(const float4*)(gg + lane * 4);
    const float4 bv = *(const float4*)(bb + lane * 4);
    int orow = row;
    if (PERM) {
        int b = row / 5120, r1 = row - b * 5120;
        int h = r1 / 80, wv = r1 - h * 80;
        int gh = h >> 3, h2 = h & 7, gw = wv >> 3, w2 = wv & 7;
        orow = ((b * 8 + h2) * 8 + w2) * 80 + gh * 10 + gw;
    }
    bf16x4 ov;
    ov[0] = (bf16_t)(d0 * rstd * gv.x + bv.x);
    ov[1] = (bf16_t)(d1 * rstd * gv.y + bv.y);
    ov[2] = (bf16_t)(d2 * rstd * gv.z + bv.z);
    ov[3] = (bf16_t)(d3 * rstd * gv.w + bv.w);
    int g   = orow >> 4, lnr = orow & 15;
    int kk  = lane >> 3;
    int q   = (lane >> 1) & 3;
    int j   = (lane & 1) * 4;
    size_t addr = (((size_t)g * 8 + kk) * 64 + q * 16 + lnr) * 8 + j;
    *(bf16x4*)(o + addr) = ov;
}

// ---------------- B-stationary streaming GEMM (no LDS, no barriers) ----------------
// 1D grid, bijective XCD swizzle (T1): blocks sharing an A-panel run consecutively on
// one XCD -> A L2/L3-hot. Wave holds B panel in regs (NT x K32T frags, NT=4 for K=256:
// 256B of A per MFMA through L1 instead of 512B). Streams M in 16-row tiles; prefetch
// unit = 4 A-frags (a0/a1), 4*NT MFMA per unit.
// EPI 0: bf16 plain out[row][N] = acc+bias                  [qkv]
// EPI 1: fp32 out = x[g] + ls*(acc+bias), grid-reverse map  [proj]
// EPI 2: h1f frag (K32out=32) = u*sigmoid(1.702u)           [fc1]
// EPI 3: fp32 out[row][256] += ls*(acc+bias)                [fc2]
template <int K32T, int NT, int EPI, int NBX>
__global__ __launch_bounds__(256) void gemm_bs(const bf16_t* __restrict__ Af,
                                               const bf16_t* __restrict__ Bf,
                                               const float* __restrict__ bias,
                                               const float* __restrict__ xres,
                                               const float* __restrict__ ls,
                                               void* __restrict__ outp, int N)
{
    constexpr int CH = K32T / 4;        // 4-frag units per tile
    constexpr int U  = 8 * CH;          // units per block pass (8 tiles)
    const int t = threadIdx.x, wid = t >> 6, lane = t & 63;
    const int ln = lane & 15, kg = lane >> 4;

    // ---- bijective XCD swizzle (gridDim.x/8 divisible by NBX)
    const int f    = blockIdx.x;
    const int xcd  = f & 7, j = f >> 3;
    const int byx  = (gridDim.x >> 3) / NBX;        // NBY/8
    const int by   = xcd * byx + j / NBX;
    const int bx   = j % NBX;

    const int col0 = bx * (64 * NT) + wid * (16 * NT);
    const int cg0  = col0 >> 4;
    const int rg0  = by * 8;

    // ---- B stationary panel
    bf16x8 bfr[NT][K32T];
#pragma unroll
    for (int nt = 0; nt < NT; ++nt)
#pragma unroll
        for (int kk = 0; kk < K32T; ++kk)
            bfr[nt][kk] = *(const bf16x8*)(Bf + ((size_t)(cg0 + nt) * K32T + kk) * 512 + lane * 8);

    const f32x4 fz = {0.f, 0.f, 0.f, 0.f};
    f32x4 acc[NT];
#pragma unroll
    for (int nt = 0; nt < NT; ++nt) acc[nt] = fz;

    bf16x8 a0[4], a1[4];

    auto lda = [&](bf16x8 (&af)[4], int u) {
        const int tile = u / CH, ch = u % CH;
#pragma unroll
        for (int k8 = 0; k8 < 4; ++k8)
            af[k8] = *(const bf16x8*)(Af + ((size_t)(rg0 + tile) * K32T + ch * 4 + k8) * 512 + lane * 8);
    };

    auto work = [&](bf16x8 (&af)[4], int u) {
        const int tile = u / CH, ch = u % CH;
        if (ch == 0) {
#pragma unroll
            for (int nt = 0; nt < NT; ++nt) acc[nt] = fz;
        }
#pragma unroll
        for (int k8 = 0; k8 < 4; ++k8)
#pragma unroll
            for (int nt = 0; nt < NT; ++nt)
                acc[nt] = __builtin_amdgcn_mfma_f32_16x16x32_bf16(af[k8], bfr[nt][ch * 4 + k8], acc[nt], 0, 0, 0);
        if (ch == CH - 1) {
            const int rowb = by * 128 + tile * 16 + kg * 4;
#pragma unroll
            for (int nt = 0; nt < NT; ++nt) {
                const int col = col0 + nt * 16 + ln;
                const f32x4 a = acc[nt];
                const float bsv = bias[col];
                if constexpr (EPI == 0) {
                    bf16_t* o = (bf16_t*)outp;
#pragma unroll
                    for (int r = 0; r < 4; ++r)
                        o[(size_t)(rowb + r) * N + col] = (bf16_t)(a[r] + bsv);
                } else if constexpr (EPI == 1) {
                    const float lsv = ls[col];
                    float* o = (float*)outp;
#pragma unroll
                    for (int r = 0; r < 4; ++r) {
                        int g = map_p_to_g(rowb + r);
                        size_t idx = (size_t)g * 256 + col;
                        o[idx] = xres[idx] + lsv * (a[r] + bsv);
                    }
                } else if constexpr (EPI == 2) {
                    bf16_t* o = (bf16_t*)outp;   // h1f frag layout, K32out=32
                    const int gq = (col & 31) >> 3, jq = col & 7, kkq = col >> 5;
#pragma unroll
                    for (int r = 0; r < 4; ++r) {
                        float u2 = a[r] + bsv;
                        // GELU ~= u*sigmoid(1.702u); abs err ~0.02 ~ bf16 rounding of h1,
                        // scaled 1e-5 downstream -> ~1e-7 at output. NaN-safe at +-inf.
                        float gl = u2 / (1.f + __expf(-1.702f * u2));
                        int row = rowb + r;
                        size_t addr = (((size_t)(row >> 4) * 32 + kkq) * 64 + gq * 16 + (row & 15)) * 8 + jq;
                        o[addr] = (bf16_t)gl;
                    }
                } else {
                    const float lsv = ls[col];
                    float* o = (float*)outp;
#pragma unroll
                    for (int r = 0; r < 4; ++r) {
                        size_t idx = (size_t)(rowb + r) * 256 + col;
                        o[idx] += lsv * (a[r] + bsv);
                    }
                }
            }
        }
    };

    lda(a0, 0);
#pragma unroll
    for (int u = 0; u < U; u += 2) {
        if (u + 1 < U) lda(a1, u + 1);
        work(a0, u);
        if (u + 2 < U) lda(a0, u + 2);
        if (u + 1 < U) work(a1, u + 1);
    }
}

// ---------------- fused per-window attention ----------------
// Inputs: plain qkv [81920][768]. Output: attno in FRAG layout (proj's A), K32=8.
__global__ __launch_bounds__(256) void attn_k(const bf16_t* __restrict__ qkv,
                                              bf16_t* __restrict__ out)
{
    __shared__ bf16_t Plds[4 * 7040];
    const int t = threadIdx.x, wid = t >> 6, lane = t & 63;
    const int ln = lane & 15, kg = lane >> 4;
    bf16_t* P = &Plds[wid * 7040];
    const int w = blockIdx.x;
    const bf16_t* base = qkv + (size_t)w * 80 * 768;
    const float SCALE = 0.17677669529663689f;

    for (int hh = 0; hh < 2; ++hh) {
        const int h = wid + hh * 4;
        const bf16_t* hb = base + h * 96;
        bf16x8 qa[5], kb[5];
#pragma unroll
        for (int mt = 0; mt < 5; ++mt)
            qa[mt] = *(const bf16x8*)(hb + (size_t)(mt * 16 + ln) * 768 + kg * 8);
#pragma unroll
        for (int nt = 0; nt < 5; ++nt)
            kb[nt] = *(const bf16x8*)(hb + (size_t)(nt * 16 + ln) * 768 + 32 + kg * 8);
        f32x4 S[5][5];
#pragma unroll
        for (int mt = 0; mt < 5; ++mt)
#pragma unroll
            for (int nt = 0; nt < 5; ++nt) {
                f32x4 z = {0.f, 0.f, 0.f, 0.f};
                S[mt][nt] = __builtin_amdgcn_mfma_f32_16x16x32_bf16(qa[mt], kb[nt], z, 0, 0, 0);
            }
#pragma unroll
        for (int mt = 0; mt < 5; ++mt) {
#pragma unroll
            for (int r = 0; r < 4; ++r) {
                float mx = S[mt][0][r];
#pragma unroll
                for (int nt = 1; nt < 5; ++nt) mx = fmaxf(mx, S[mt][nt][r]);
                mx = fmaxf(mx, __shfl_xor(mx, 1, 64));
                mx = fmaxf(mx, __shfl_xor(mx, 2, 64));
                mx = fmaxf(mx, __shfl_xor(mx, 4, 64));
                mx = fmaxf(mx, __shfl_xor(mx, 8, 64));
                float sum = 0.f;
#pragma unroll
                for (int nt = 0; nt < 5; ++nt) {
                    float e = __expf((S[mt][nt][r] - mx) * SCALE);
                    S[mt][nt][r] = e;
                    sum += e;
                }
                sum += __shfl_xor(sum, 1, 64);
                sum += __shfl_xor(sum, 2, 64);
                sum += __shfl_xor(sum, 4, 64);
                sum += __shfl_xor(sum, 8, 64);
                float inv = 1.f / sum;
#pragma unroll
                for (int nt = 0; nt < 5; ++nt) S[mt][nt][r] *= inv;
            }
        }
#pragma unroll
        for (int mt = 0; mt < 5; ++mt)
#pragma unroll
            for (int nt = 0; nt < 5; ++nt)
#pragma unroll
                for (int r = 0; r < 4; ++r)
                    P[(mt * 16 + kg * 4 + r) * 88 + nt * 16 + ln] = (bf16_t)S[mt][nt][r];
        f32x4 O[5][2];
#pragma unroll
        for (int mt = 0; mt < 5; ++mt) {
            O[mt][0] = (f32x4){0.f, 0.f, 0.f, 0.f};
            O[mt][1] = (f32x4){0.f, 0.f, 0.f, 0.f};
        }
#pragma unroll
        for (int nt2 = 0; nt2 < 2; ++nt2) {
#pragma unroll
            for (int kt = 0; kt < 3; ++kt) {
                const bool dead = (kt == 2) && (kg >= 2);
                bf16x8 bv;
#pragma unroll
                for (int j = 0; j < 8; ++j) {
                    int tok = kt * 32 + kg * 8 + j;
                    if (tok > 79) tok = 79;
                    bv[j] = hb[(size_t)tok * 768 + 64 + nt2 * 16 + ln];
                }
                if (dead) {
#pragma unroll
                    for (int j = 0; j < 8; ++j) bv[j] = (bf16_t)0.f;
                }
                int cb = kt * 32 + kg * 8;
                if (cb >= 80) cb = 0;
#pragma unroll
                for (int mt = 0; mt < 5; ++mt) {
                    bf16x8 av = *(const bf16x8*)(P + (mt * 16 + ln) * 88 + cb);
                    O[mt][nt2] = __builtin_amdgcn_mfma_f32_16x16x32_bf16(av, bv, O[mt][nt2], 0, 0, 0);
                }
            }
        }
#pragma unroll
        for (int mt = 0; mt < 5; ++mt)
#pragma unroll
            for (int nt2 = 0; nt2 < 2; ++nt2) {
                const int q16 = nt2 * 2 + (ln >> 3);
#pragma unroll
                for (int r = 0; r < 4; ++r) {
                    size_t addr = ((((size_t)w * 5 + mt) * 8 + h) * 64 + q16 * 16 + kg * 4 + r) * 8 + (ln & 7);
                    out[addr] = (bf16_t)O[mt][nt2][r];
                }
            }
    }
}

// ---------------- launch ----------------
extern "C" void kernel_launch(void* const* d_in, const int* in_sizes, int n_in,
                              void* d_out, int out_size, void* d_ws, size_t ws_size,
                              hipStream_t stream)
{
    (void)in_sizes; (void)n_in; (void)out_size; (void)ws_size;
    const float* x     = (const float*)d_in[0];
    const float* n1g   = (const float*)d_in[1];
    const float* n1b   = (const float*)d_in[2];
    const float* qkvw  = (const float*)d_in[3];
    const float* qkvb  = (const float*)d_in[4];
    const float* projw = (const float*)d_in[5];
    const float* projb = (const float*)d_in[6];
    const float* ls1   = (const float*)d_in[7];
    const float* n2g   = (const float*)d_in[8];
    const float* n2b   = (const float*)d_in[9];
    const float* fc1w  = (const float*)d_in[10];
    const float* fc1b  = (const float*)d_in[11];
    const float* fc2w  = (const float*)d_in[12];
    const float* fc2b  = (const float*)d_in[13];
    const float* ls2   = (const float*)d_in[14];
    float* out = (float*)d_out;

    // ws layout (bytes):
    //  [0, 42MB)      actA: ln1p-frag -> attno-frag -> ln2-frag (sequential reuse)
    //  [42, 210MB)    big: qkv plain (126MB) -> h1f frag (168MB) (sequential reuse)
    //  [210MB, ...)   frag weights ~1.6MB
    char* ws = (char*)d_ws;
    bf16_t* actA   = (bf16_t*)(ws);
    bf16_t* qkv    = (bf16_t*)(ws + 41943040ull);
    bf16_t* h1f    = (bf16_t*)(ws + 41943040ull);
    bf16_t* wbuf   = (bf16_t*)(ws + 209715200ull);
    bf16_t* qkvwt  = wbuf;                          // frag [768][256]
    bf16_t* projwt = qkvwt + 768 * 256;             // frag [256][256]
    bf16_t* fc1wt  = projwt + 256 * 256;            // frag [1024][256]
    bf16_t* fc2wt  = fc1wt + 1024 * 256;            // frag [256][1024]

    wconv_k<<<96,  256, 0, stream>>>(qkvw,  qkvwt, 768, 8);
    wconv_k<<<32,  256, 0, stream>>>(projw, projwt, 256, 8);
    wconv_k<<<128, 256, 0, stream>>>(fc1w,  fc1wt, 1024, 8);
    wconv_k<<<128, 256, 0, stream>>>(fc2w,  fc2wt, 256, 32);

    ln_k<1><<<20480, 256, 0, stream>>>(x, n1g, n1b, actA);
    gemm_bs<8, 4, 0, 3><<<1920, 256, 0, stream>>>(actA, qkvwt, qkvb, nullptr, nullptr, qkv, 768);
    attn_k<<<1024, 256, 0, stream>>>(qkv, actA);
    gemm_bs<8, 4, 1, 1><<<640, 256, 0, stream>>>(actA, projwt, projb, x, ls1, out, 256);
    ln_k<0><<<20480, 256, 0, stream>>>(out, n2g, n2b, actA);
    gemm_bs<8, 4, 2, 4><<<2560, 256, 0, stream>>>(actA, fc1wt, fc1b, nullptr, nullptr, h1f, 1024);
    gemm_bs<32, 1, 3, 4><<<2560, 256, 0, stream>>>(h1f, fc2wt, fc2b, nullptr, ls2, out, 256);
}

// Round 9
// 488.815 us; speedup vs baseline: 1.4183x; 1.4183x over previous
//
#include <hip/hip_runtime.h>
#include <hip/hip_bf16.h>
#include <stdint.h>
#include <math.h>

typedef __bf16 bf16_t;
typedef __bf16 bf16x8 __attribute__((ext_vector_type(8)));
typedef __bf16 bf16x4 __attribute__((ext_vector_type(4)));
typedef float  f32x4  __attribute__((ext_vector_type(4)));

typedef __attribute__((address_space(1))) const void global_cv;
typedef __attribute__((address_space(3))) void lds_v;

// Problem constants: B=16,H=64,W=80,C=256; GH=8,GW=10; heads=8,DH=32; INNER=1024

__device__ __forceinline__ int map_p_to_g(int p) {
    int w = p / 80, n = p - w * 80;
    int b  = w >> 6, h2 = (w >> 3) & 7, w2 = w & 7;
    int gh = n / 10, gw = n - gh * 10;
    return b * 5120 + (gh * 8 + h2) * 80 + (gw * 8 + w2);
}

// XOR swizzle for 128-B LDS rows: bits 4-6 ^= bits 7-9 (involution, keeps 16B align)
__device__ __forceinline__ int swz128(int b) { return b ^ (((b >> 7) & 7) << 4); }

// ---------------- weight convert+transpose: fp32 [K][N] -> bf16 [N][K] ----------------
__global__ __launch_bounds__(256) void wconv_k(const float* __restrict__ in,
                                               bf16_t* __restrict__ out, int N, int K)
{
    int i = blockIdx.x * 256 + threadIdx.x;
    int n = i / K, k = i - n * K;
    out[i] = (bf16_t)in[(size_t)k * N + n];
}

// ---------------- LayerNorm (one wave per row), optional partition permute ----------------
template <int PERM>
__global__ __launch_bounds__(256) void ln_k(const float* __restrict__ in,
                                            const float* __restrict__ gg,
                                            const float* __restrict__ bb,
                                            bf16_t* __restrict__ o)
{
    int row  = blockIdx.x * 4 + (threadIdx.x >> 6);
    int lane = threadIdx.x & 63;
    const float4 xv = *(const float4*)(in + (size_t)row * 256 + lane * 4);
    float s = xv.x + xv.y + xv.z + xv.w;
#pragma unroll
    for (int m = 1; m < 64; m <<= 1) s += __shfl_xor(s, m, 64);
    float mean = s * (1.f / 256.f);
    float d0 = xv.x - mean, d1 = xv.y - mean, d2 = xv.z - mean, d3 = xv.w - mean;
    float v = d0 * d0 + d1 * d1 + d2 * d2 + d3 * d3;
#pragma unroll
    for (int m = 1; m < 64; m <<= 1) v += __shfl_xor(v, m, 64);
    float rstd = rsqrtf(v * (1.f / 256.f) + 1e-5f);
    const float4 gv = *(const float4*)(gg + lane * 4);
    const float4 bv = *(const float4*)(bb + lane * 4);
    int orow = row;
    if (PERM) {
        int b = row / 5120, r1 = row - b * 5120;
        int h = r1 / 80, wv = r1 - h * 80;
        int gh = h >> 3, h2 = h & 7, gw = wv >> 3, w2 = wv & 7;
        orow = ((b * 8 + h2) * 8 + w2) * 80 + gh * 10 + gw;
    }
    bf16x4 ov;
    ov[0] = (bf16_t)(d0 * rstd * gv.x + bv.x);
    ov[1] = (bf16_t)(d1 * rstd * gv.y + bv.y);
    ov[2] = (bf16_t)(d2 * rstd * gv.z + bv.z);
    ov[3] = (bf16_t)(d3 * rstd * gv.w + bv.w);
    *(bf16x4*)(o + (size_t)orow * 256 + lane * 4) = ov;
}

// ---------------- 256x256-tile 2-phase MFMA GEMM (8 waves, BK=64) ----------------
// Proven regime (m230/m248 ~655-682 TF): 64 MFMA/wave per drain, gload_lds staging,
// both-sides swz128 (rule 21), double-buffered LDS (128 KB), XCD-bijective 1D grid.
// Wave (wr,wc) of 2x4 owns 128x64; acc[8][4] f32x4.
// EPI 0: bf16 out[row][N] = acc+bias                        [qkv]
// EPI 1: fp32 out = x[g] + ls*(acc+bias), grid-reverse map  [proj]
// EPI 2: bf16 out[row][N] = gelu_sig(acc+bias)              [fc1]
// EPI 3: fp32 out[row][256] += ls*(acc+bias)                [fc2]
template <int EPI, int NBX>
__device__ __forceinline__ void gemm_body(const bf16_t* __restrict__ A,
                                          const bf16_t* __restrict__ Bt,
                                          const float* __restrict__ bias,
                                          const float* __restrict__ xres,
                                          const float* __restrict__ ls,
                                          void* __restrict__ outp,
                                          int N, int K)
{
    __shared__ bf16_t At[2][16384];   // [buf][256 rows x 128 B]
    __shared__ bf16_t Bl[2][16384];
    const int t = threadIdx.x;
    const int wid = t >> 6, lane = t & 63;
    const int wr = wid >> 2, wc = wid & 3;
    const int ln = lane & 15, kg = lane >> 4;

    // bijective XCD swizzle: grid = NBY*NBX, NBY multiple of 8
    const int f   = blockIdx.x;
    const int xcd = f & 7, jj = f >> 3;
    const int byx = (gridDim.x >> 3) / NBX;
    const int by  = xcd * byx + jj / NBX;
    const int bx  = jj % NBX;

    const size_t Kb = (size_t)K * 2;
    const char* Ab = (const char*)(A  + (size_t)by * 256 * K);
    const char* Bb = (const char*)(Bt + (size_t)bx * 256 * K);
    char* AtB = (char*)At;
    char* BlB = (char*)Bl;

    const f32x4 fz = {0.f, 0.f, 0.f, 0.f};
    f32x4 acc[8][4];
#pragma unroll
    for (int i = 0; i < 8; ++i)
#pragma unroll
        for (int j = 0; j < 4; ++j) acc[i][j] = fz;

    const int nsteps = K >> 6;

    auto stage = [&](int s, int buf) {
        const size_t kb = (size_t)s * 128;
        char* Ad = AtB + buf * 32768;
        char* Bd = BlB + buf * 32768;
#pragma unroll
        for (int i = 0; i < 4; ++i) {
            int p   = i * 8192 + t * 16;
            int row = p >> 7;
            int off = (p & 127) ^ ((row & 7) << 4);   // inverse-swizzled source
            __builtin_amdgcn_global_load_lds((global_cv*)(Ab + (size_t)row * Kb + kb + off),
                                             (lds_v*)(Ad + p), 16, 0, 0);
            __builtin_amdgcn_global_load_lds((global_cv*)(Bb + (size_t)row * Kb + kb + off),
                                             (lds_v*)(Bd + p), 16, 0, 0);
        }
    };

    stage(0, 0);
    __syncthreads();

    for (int s = 0; s < nsteps; ++s) {
        const int cur = s & 1;
        if (s + 1 < nsteps) stage(s + 1, cur ^ 1);
        const char* Ac = AtB + cur * 32768;
        const char* Bc = BlB + cur * 32768;
#pragma unroll
        for (int kk = 0; kk < 2; ++kk) {
            bf16x8 av[8], bv[4];
#pragma unroll
            for (int mt = 0; mt < 8; ++mt) {
                int row = wr * 128 + mt * 16 + ln;
                av[mt] = *(const bf16x8*)(Ac + swz128(row * 128 + kk * 64 + kg * 16));
            }
#pragma unroll
            for (int nt = 0; nt < 4; ++nt) {
                int row = wc * 64 + nt * 16 + ln;
                bv[nt] = *(const bf16x8*)(Bc + swz128(row * 128 + kk * 64 + kg * 16));
            }
#pragma unroll
            for (int mt = 0; mt < 8; ++mt)
#pragma unroll
                for (int nt = 0; nt < 4; ++nt)
                    acc[mt][nt] = __builtin_amdgcn_mfma_f32_16x16x32_bf16(av[mt], bv[nt], acc[mt][nt], 0, 0, 0);
        }
        __syncthreads();   // drains stage vmcnt + protects buffer swap
    }

#pragma unroll
    for (int mt = 0; mt < 8; ++mt) {
        const int rowb = by * 256 + wr * 128 + mt * 16 + kg * 4;
#pragma unroll
        for (int nt = 0; nt < 4; ++nt) {
            const int col = bx * 256 + wc * 64 + nt * 16 + ln;
            const f32x4 a = acc[mt][nt];
            const float bsv = bias[col];
            if constexpr (EPI == 0) {
                bf16_t* o = (bf16_t*)outp;
#pragma unroll
                for (int r = 0; r < 4; ++r)
                    o[(size_t)(rowb + r) * N + col] = (bf16_t)(a[r] + bsv);
            } else if constexpr (EPI == 1) {
                const float lsv = ls[col];
                float* o = (float*)outp;
#pragma unroll
                for (int r = 0; r < 4; ++r) {
                    int g = map_p_to_g(rowb + r);
                    size_t idx = (size_t)g * 256 + col;
                    o[idx] = xres[idx] + lsv * (a[r] + bsv);
                }
            } else if constexpr (EPI == 2) {
                bf16_t* o = (bf16_t*)outp;
#pragma unroll
                for (int r = 0; r < 4; ++r) {
                    float u2 = a[r] + bsv;
                    // GELU ~= u*sigmoid(1.702u); err ~0.02 ~ bf16 rounding, x1e-5 downstream
                    float gl = u2 / (1.f + __expf(-1.702f * u2));
                    o[(size_t)(rowb + r) * N + col] = (bf16_t)gl;
                }
            } else {
                const float lsv = ls[col];
                float* o = (float*)outp;
#pragma unroll
                for (int r = 0; r < 4; ++r) {
                    size_t idx = (size_t)(rowb + r) * 256 + col;
                    o[idx] += lsv * (a[r] + bsv);
                }
            }
        }
    }
}

__global__ __launch_bounds__(512) void gq_k(const bf16_t* A, const bf16_t* Bt, const float* bias,
                                            void* outp, int N, int K)
{ gemm_body<0, 3>(A, Bt, bias, nullptr, nullptr, outp, N, K); }

__global__ __launch_bounds__(512) void gp_k(const bf16_t* A, const bf16_t* Bt, const float* bias,
                                            const float* xres, const float* ls, void* outp, int N, int K)
{ gemm_body<1, 1>(A, Bt, bias, xres, ls, outp, N, K); }

__global__ __launch_bounds__(512) void g1_k(const bf16_t* A, const bf16_t* Bt, const float* bias,
                                            void* outp, int N, int K)
{ gemm_body<2, 4>(A, Bt, bias, nullptr, nullptr, outp, N, K); }

__global__ __launch_bounds__(512) void g2_k(const bf16_t* A, const bf16_t* Bt, const float* bias,
                                            const float* ls, void* outp, int N, int K)
{ gemm_body<3, 1>(A, Bt, bias, nullptr, ls, outp, N, K); }

// ---------------- fused per-window attention (plain qkv in, plain attno out) ----------------
__global__ __launch_bounds__(256) void attn_k(const bf16_t* __restrict__ qkv,
                                              bf16_t* __restrict__ out)
{
    __shared__ bf16_t Plds[4 * 7040];
    const int t = threadIdx.x, wid = t >> 6, lane = t & 63;
    const int ln = lane & 15, kg = lane >> 4;
    bf16_t* P = &Plds[wid * 7040];
    const int w = blockIdx.x;
    const bf16_t* base = qkv + (size_t)w * 80 * 768;
    const float SCALE = 0.17677669529663689f;

    for (int hh = 0; hh < 2; ++hh) {
        const int h = wid + hh * 4;
        const bf16_t* hb = base + h * 96;
        bf16x8 qa[5], kb[5];
#pragma unroll
        for (int mt = 0; mt < 5; ++mt)
            qa[mt] = *(const bf16x8*)(hb + (size_t)(mt * 16 + ln) * 768 + kg * 8);
#pragma unroll
        for (int nt = 0; nt < 5; ++nt)
            kb[nt] = *(const bf16x8*)(hb + (size_t)(nt * 16 + ln) * 768 + 32 + kg * 8);
        f32x4 S[5][5];
#pragma unroll
        for (int mt = 0; mt < 5; ++mt)
#pragma unroll
            for (int nt = 0; nt < 5; ++nt) {
                f32x4 z = {0.f, 0.f, 0.f, 0.f};
                S[mt][nt] = __builtin_amdgcn_mfma_f32_16x16x32_bf16(qa[mt], kb[nt], z, 0, 0, 0);
            }
#pragma unroll
        for (int mt = 0; mt < 5; ++mt) {
#pragma unroll
            for (int r = 0; r < 4; ++r) {
                float mx = S[mt][0][r];
#pragma unroll
                for (int nt = 1; nt < 5; ++nt) mx = fmaxf(mx, S[mt][nt][r]);
                mx = fmaxf(mx, __shfl_xor(mx, 1, 64));
                mx = fmaxf(mx, __shfl_xor(mx, 2, 64));
                mx = fmaxf(mx, __shfl_xor(mx, 4, 64));
                mx = fmaxf(mx, __shfl_xor(mx, 8, 64));
                float sum = 0.f;
#pragma unroll
                for (int nt = 0; nt < 5; ++nt) {
                    float e = __expf((S[mt][nt][r] - mx) * SCALE);
                    S[mt][nt][r] = e;
                    sum += e;
                }
                sum += __shfl_xor(sum, 1, 64);
                sum += __shfl_xor(sum, 2, 64);
                sum += __shfl_xor(sum, 4, 64);
                sum += __shfl_xor(sum, 8, 64);
                float inv = 1.f / sum;
#pragma unroll
                for (int nt = 0; nt < 5; ++nt) S[mt][nt][r] *= inv;
            }
        }
#pragma unroll
        for (int mt = 0; mt < 5; ++mt)
#pragma unroll
            for (int nt = 0; nt < 5; ++nt)
#pragma unroll
                for (int r = 0; r < 4; ++r)
                    P[(mt * 16 + kg * 4 + r) * 88 + nt * 16 + ln] = (bf16_t)S[mt][nt][r];
        f32x4 O[5][2];
#pragma unroll
        for (int mt = 0; mt < 5; ++mt) {
            O[mt][0] = (f32x4){0.f, 0.f, 0.f, 0.f};
            O[mt][1] = (f32x4){0.f, 0.f, 0.f, 0.f};
        }
#pragma unroll
        for (int nt2 = 0; nt2 < 2; ++nt2) {
#pragma unroll
            for (int kt = 0; kt < 3; ++kt) {
                const bool dead = (kt == 2) && (kg >= 2);
                bf16x8 bv;
#pragma unroll
                for (int j = 0; j < 8; ++j) {
                    int tok = kt * 32 + kg * 8 + j;
                    if (tok > 79) tok = 79;
                    bv[j] = hb[(size_t)tok * 768 + 64 + nt2 * 16 + ln];
                }
                if (dead) {
#pragma unroll
                    for (int j = 0; j < 8; ++j) bv[j] = (bf16_t)0.f;
                }
                int cb = kt * 32 + kg * 8;
                if (cb >= 80) cb = 0;
#pragma unroll
                for (int mt = 0; mt < 5; ++mt) {
                    bf16x8 av = *(const bf16x8*)(P + (mt * 16 + ln) * 88 + cb);
                    O[mt][nt2] = __builtin_amdgcn_mfma_f32_16x16x32_bf16(av, bv, O[mt][nt2], 0, 0, 0);
                }
            }
        }
#pragma unroll
        for (int mt = 0; mt < 5; ++mt)
#pragma unroll
            for (int nt2 = 0; nt2 < 2; ++nt2)
#pragma unroll
                for (int r = 0; r < 4; ++r) {
                    int n = mt * 16 + kg * 4 + r;
                    out[((size_t)w * 80 + n) * 256 + h * 32 + nt2 * 16 + ln] = (bf16_t)O[mt][nt2][r];
                }
    }
}

// ---------------- launch ----------------
extern "C" void kernel_launch(void* const* d_in, const int* in_sizes, int n_in,
                              void* d_out, int out_size, void* d_ws, size_t ws_size,
                              hipStream_t stream)
{
    (void)in_sizes; (void)n_in; (void)out_size; (void)ws_size;
    const float* x     = (const float*)d_in[0];
    const float* n1g   = (const float*)d_in[1];
    const float* n1b   = (const float*)d_in[2];
    const float* qkvw  = (const float*)d_in[3];
    const float* qkvb  = (const float*)d_in[4];
    const float* projw = (const float*)d_in[5];
    const float* projb = (const float*)d_in[6];
    const float* ls1   = (const float*)d_in[7];
    const float* n2g   = (const float*)d_in[8];
    const float* n2b   = (const float*)d_in[9];
    const float* fc1w  = (const float*)d_in[10];
    const float* fc1b  = (const float*)d_in[11];
    const float* fc2w  = (const float*)d_in[12];
    const float* fc2b  = (const float*)d_in[13];
    const float* ls2   = (const float*)d_in[14];
    float* out = (float*)d_out;

    // ws (bytes): [0,42MB) actA: ln1p -> attno -> ln2 (sequential reuse)
    //             [42,210MB) big: qkv plain 126MB -> h1 plain 168MB (sequential reuse)
    //             [210MB,..) transposed bf16 weights ~1.5MB
    char* ws = (char*)d_ws;
    bf16_t* actA   = (bf16_t*)(ws);
    bf16_t* qkv    = (bf16_t*)(ws + 41943040ull);
    bf16_t* h1     = (bf16_t*)(ws + 41943040ull);
    bf16_t* wbuf   = (bf16_t*)(ws + 209715200ull);
    bf16_t* qkvwt  = wbuf;                          // [768][256]
    bf16_t* projwt = qkvwt + 768 * 256;             // [256][256]
    bf16_t* fc1wt  = projwt + 256 * 256;            // [1024][256]
    bf16_t* fc2wt  = fc1wt + 1024 * 256;            // [256][1024]

    wconv_k<<<768,  256, 0, stream>>>(qkvw,  qkvwt, 768, 256);
    wconv_k<<<256,  256, 0, stream>>>(projw, projwt, 256, 256);
    wconv_k<<<1024, 256, 0, stream>>>(fc1w,  fc1wt, 1024, 256);
    wconv_k<<<1024, 256, 0, stream>>>(fc2w,  fc2wt, 256, 1024);

    ln_k<1><<<20480, 256, 0, stream>>>(x, n1g, n1b, actA);
    gq_k<<<960, 512, 0, stream>>>(actA, qkvwt, qkvb, qkv, 768, 256);          // 320x3 blocks
    attn_k<<<1024, 256, 0, stream>>>(qkv, actA);
    gp_k<<<320, 512, 0, stream>>>(actA, projwt, projb, x, ls1, out, 256, 256);
    ln_k<0><<<20480, 256, 0, stream>>>(out, n2g, n2b, actA);
    g1_k<<<1280, 512, 0, stream>>>(actA, fc1wt, fc1b, h1, 1024, 256);         // 320x4 blocks
    g2_k<<<320, 512, 0, stream>>>(h1, fc2wt, fc2b, ls2, out, 256, 1024);
}